// Round 3
// 677.986 us; speedup vs baseline: 1.2727x; 1.2727x over previous
//
#include <hip/hip_runtime.h>
#include <hip/hip_bf16.h>

typedef __hip_bfloat16 bf16;
typedef unsigned short u16;
typedef __attribute__((ext_vector_type(8))) short short8;
typedef __attribute__((ext_vector_type(4))) float f32x4;

#define BN_EPS 1e-5f

__device__ __forceinline__ float b2f(bf16 v) { return __bfloat162float(v); }
__device__ __forceinline__ u16 f2bs(float f) {
    bf16 h = __float2bfloat16(f);
    u16 s; __builtin_memcpy(&s, &h, 2); return s;
}
__device__ __forceinline__ void gl_lds16(const void* g, void* l) {
    __builtin_amdgcn_global_load_lds(
        (const __attribute__((address_space(1))) unsigned int*)g,
        (__attribute__((address_space(3))) unsigned int*)l, 16, 0, 0);
}

// ---------------------------------------------------------------------------
// One-time weight convert: w_qkv fp32 [768][1024] -> bf16, w_proj fp32
// [256][512] -> bf16.  917504 elems total, 896 blocks x 256 thr x 4 elems.
// ---------------------------------------------------------------------------
__global__ __launch_bounds__(256) void k_wconv(
    const float* __restrict__ wq_f, const float* __restrict__ wp_f,
    u16* __restrict__ wq, u16* __restrict__ wp)
{
    const int i = (blockIdx.x * 256 + threadIdx.x) * 4;
    if (i < 786432) {
        const float4 v = *(const float4*)(wq_f + i);
        *(ushort4*)(wq + i) = make_ushort4(f2bs(v.x), f2bs(v.y), f2bs(v.z), f2bs(v.w));
    } else {
        const int j = i - 786432;
        const float4 v = *(const float4*)(wp_f + j);
        *(ushort4*)(wp + j) = make_ushort4(f2bs(v.x), f2bs(v.y), f2bs(v.z), f2bs(v.w));
    }
}

// ---------------------------------------------------------------------------
// Patchify: x fp32 [16,256,128,128] -> xt bf16 [n][k] for half a batch.
//   n = (b-b_base)*4096 + oh*64 + ow, k = ci*4 + kh*2 + kw (1024).
// Channel-paired: each iter handles (ci, ci+1) -> one 16B store.
// ---------------------------------------------------------------------------
__global__ __launch_bounds__(256) void k_patchify(
    const float* __restrict__ x, u16* __restrict__ xt, int b_base)
{
    const int blk = blockIdx.x;              // 512 = 8 b * 64 oh
    const int b_rel = blk >> 6, oh = blk & 63;
    const int b = b_base + b_rel;
    const int ow = threadIdx.x & 63, cp = threadIdx.x >> 6;   // cp in [0,4)
    u16* orow = xt + ((size_t)b_rel * 4096 + oh * 64 + ow) * 1024;
    const float* xb = x + (size_t)b * 256 * 16384 + (2 * oh) * 128 + 2 * ow;
    for (int ci = cp * 2; ci < 256; ci += 8) {     // even ci: pair (ci, ci+1)
        const float* p0 = xb + (size_t)ci * 16384;
        const float* p1 = p0 + 16384;
        const float2 a0 = *(const float2*)p0;
        const float2 a1 = *(const float2*)(p0 + 128);
        const float2 b0 = *(const float2*)p1;
        const float2 b1 = *(const float2*)(p1 + 128);
        short8 v;
        v[0] = (short)f2bs(a0.x); v[1] = (short)f2bs(a0.y);
        v[2] = (short)f2bs(a1.x); v[3] = (short)f2bs(a1.y);
        v[4] = (short)f2bs(b0.x); v[5] = (short)f2bs(b0.y);
        v[6] = (short)f2bs(b1.x); v[7] = (short)f2bs(b1.y);
        *(short8*)(orow + ci * 4) = v;
    }
}

// ---------------------------------------------------------------------------
// Conv GEMM (operand-swapped): C[m=co][n=pos] = sum_k wq[co][k]*xt[pos][k],
// +BN, writes qkvT[b][s][co] (co contiguous -> ushort4 stores, 4 co in regs).
// Both operands bf16 via global_load_lds.  Grid (256 n-blocks, 6 m-blocks).
// ---------------------------------------------------------------------------
__global__ __launch_bounds__(256) void k_conv_gemm(
    const u16* __restrict__ wq, const u16* __restrict__ xt,
    const float* __restrict__ gamma, const float* __restrict__ beta,
    u16* __restrict__ qkvT, int b_base)
{
    __shared__ u16 sA[128][32];   // wq tile [co][k]
    __shared__ u16 sB[128][32];   // xt tile [pos][k]
    const int tid = threadIdx.x;
    const int lane = tid & 63, wave = tid >> 6;
    const int wm = (wave >> 1) * 64, wn = (wave & 1) * 64;
    const int l15 = lane & 15, q = lane >> 4;
    const int n0 = blockIdx.x * 128, m0 = blockIdx.y * 128;

    f32x4 acc[4][4];
    #pragma unroll
    for (int mi = 0; mi < 4; ++mi)
        #pragma unroll
        for (int ni = 0; ni < 4; ++ni) acc[mi][ni] = (f32x4){0.f, 0.f, 0.f, 0.f};

    for (int k0 = 0; k0 < 1024; k0 += 32) {
        #pragma unroll
        for (int i = 0; i < 2; ++i) {            // wq: async 16B
            const int e = tid + i * 256;         // [0,512)
            const int ml = e >> 2, ch = e & 3;
            gl_lds16(wq + (size_t)(m0 + ml) * 1024 + k0 + ch * 8,
                     &sA[0][0] + (size_t)e * 8);
        }
        #pragma unroll
        for (int i = 0; i < 2; ++i) {            // xt: async 16B
            const int e = tid + i * 256;         // [0,512)
            const int nl = e >> 2, ch = e & 3;
            gl_lds16(xt + (size_t)(n0 + nl) * 1024 + k0 + ch * 8,
                     &sB[0][0] + (size_t)e * 8);
        }
        __syncthreads();
        short8 af[4], bf[4];
        #pragma unroll
        for (int mi = 0; mi < 4; ++mi) af[mi] = *(const short8*)&sA[wm + mi * 16 + l15][q * 8];
        #pragma unroll
        for (int ni = 0; ni < 4; ++ni) bf[ni] = *(const short8*)&sB[wn + ni * 16 + l15][q * 8];
        #pragma unroll
        for (int mi = 0; mi < 4; ++mi)
            #pragma unroll
            for (int ni = 0; ni < 4; ++ni)
                acc[mi][ni] = __builtin_amdgcn_mfma_f32_16x16x32_bf16(
                    af[mi], bf[ni], acc[mi][ni], 0, 0, 0);
        __syncthreads();
    }

    const float inv = rsqrtf(1.0f + BN_EPS);
    float4 g4[4], b4[4];
    #pragma unroll
    for (int mi = 0; mi < 4; ++mi) {
        const int co = m0 + wm + mi * 16 + q * 4;   // C/D row = quad*4+reg
        float4 g = *(const float4*)(gamma + co);
        g4[mi] = make_float4(g.x * inv, g.y * inv, g.z * inv, g.w * inv);
        b4[mi] = *(const float4*)(beta + co);
    }
    #pragma unroll
    for (int ni = 0; ni < 4; ++ni) {
        const int pos = n0 + wn + ni * 16 + l15;    // C/D col = lane&15
        const int b = b_base + (pos >> 12), s = pos & 4095;
        u16* row = qkvT + ((size_t)(b * 4096 + s)) * 768;
        #pragma unroll
        for (int mi = 0; mi < 4; ++mi) {
            const int co = m0 + wm + mi * 16 + q * 4;
            *(ushort4*)(row + co) = make_ushort4(
                f2bs(acc[mi][ni][0] * g4[mi].x + b4[mi].x),
                f2bs(acc[mi][ni][1] * g4[mi].y + b4[mi].y),
                f2bs(acc[mi][ni][2] * g4[mi].z + b4[mi].z),
                f2bs(acc[mi][ni][3] * g4[mi].w + b4[mi].w));
        }
    }
}

// ---------------------------------------------------------------------------
// MFMA axial attention.  qkvT[b][s][c] (c contig: 0..255 Q, 256..511 K,
// 512..767 V).  Per block (b,fix): S=K^T Q (64x64,K=256) -> reg softmax ->
// P,V through LDS -> O=V.P (256x64,K=64) -> vcatT[s][c].
//   MODE 0: row(i)=fix*64+i, out s=fix*64+qx, channels 0..255.
//   MODE 1: row(i)=i*64+fix, out s=qx*64+fix, channels 256..511.
// ---------------------------------------------------------------------------
template <int MODE>
__global__ __launch_bounds__(256) void k_attn_mfma(
    const u16* __restrict__ qkvT, u16* __restrict__ vcatT)
{
    const int b = blockIdx.x >> 6, fix = blockIdx.x & 63;
    const int tid = threadIdx.x, lane = tid & 63, wv = tid >> 6;
    const int l15 = lane & 15, q = lane >> 4;
    const u16* base = qkvT + (size_t)b * 4096 * 768;

    __shared__ u16 sV[256][72];   // V transposed: [c][w], pad 72 (2-way only)
    __shared__ u16 sP[64][72];    // probs: [qx][ky]

    // ---- V transpose: global [w][c-contig] -> LDS [c][w] ----
    {
        const int w = tid & 63, cg = tid >> 6;
        const int vrow_i = (MODE == 0) ? (fix * 64 + w) : (w * 64 + fix);
        const u16* vrow = base + (size_t)vrow_i * 768 + 512;
        #pragma unroll
        for (int it = 0; it < 8; ++it) {
            const int c0 = (cg + it * 4) * 8;
            const ushort4 lo = *(const ushort4*)(vrow + c0);
            const ushort4 hi = *(const ushort4*)(vrow + c0 + 4);
            sV[c0 + 0][w] = lo.x; sV[c0 + 1][w] = lo.y;
            sV[c0 + 2][w] = lo.z; sV[c0 + 3][w] = lo.w;
            sV[c0 + 4][w] = hi.x; sV[c0 + 5][w] = hi.y;
            sV[c0 + 6][w] = hi.z; sV[c0 + 7][w] = hi.w;
        }
    }

    // ---- Phase A: S[ky][qx] = sum_c K[c][ky] Q[c][qx].  Wave wv owns
    //      n-tile wv (qx block), all 4 m-tiles (full ky for softmax). ----
    f32x4 accS[4];
    #pragma unroll
    for (int t = 0; t < 4; ++t) accS[t] = (f32x4){0.f, 0.f, 0.f, 0.f};
    {
        const int qx = wv * 16 + l15;
        const u16* qrow = base + (size_t)((MODE == 0) ? (fix * 64 + qx) : (qx * 64 + fix)) * 768;
        const u16* krow[4];
        #pragma unroll
        for (int t = 0; t < 4; ++t) {
            const int ky = t * 16 + l15;
            krow[t] = base + (size_t)((MODE == 0) ? (fix * 64 + ky) : (ky * 64 + fix)) * 768 + 256;
        }
        for (int k0 = 0; k0 < 256; k0 += 32) {
            const short8 bq = *(const short8*)(qrow + k0 + q * 8);
            #pragma unroll
            for (int t = 0; t < 4; ++t) {
                const short8 ak = *(const short8*)(krow[t] + k0 + q * 8);
                accS[t] = __builtin_amdgcn_mfma_f32_16x16x32_bf16(ak, bq, accS[t], 0, 0, 0);
            }
        }
    }

    // ---- register softmax over ky (16 in-lane vals x 4 quad-lanes) ----
    {
        float m = -1e30f;
        #pragma unroll
        for (int t = 0; t < 4; ++t)
            #pragma unroll
            for (int r = 0; r < 4; ++r) m = fmaxf(m, accS[t][r]);
        m = fmaxf(m, __shfl_xor(m, 16, 64));
        m = fmaxf(m, __shfl_xor(m, 32, 64));
        m *= 0.0625f;
        float sum = 0.f;
        #pragma unroll
        for (int t = 0; t < 4; ++t)
            #pragma unroll
            for (int r = 0; r < 4; ++r) {
                const float e = __expf(accS[t][r] * 0.0625f - m);
                accS[t][r] = e; sum += e;
            }
        sum += __shfl_xor(sum, 16, 64);
        sum += __shfl_xor(sum, 32, 64);
        const float rinv = 1.0f / sum;
        const int qx = wv * 16 + l15;
        #pragma unroll
        for (int t = 0; t < 4; ++t) {
            // lane holds ky = t*16 + q*4 + r (C/D row), fixed qx (C/D col)
            *(ushort4*)&sP[qx][t * 16 + q * 4] = make_ushort4(
                f2bs(accS[t][0] * rinv), f2bs(accS[t][1] * rinv),
                f2bs(accS[t][2] * rinv), f2bs(accS[t][3] * rinv));
        }
    }
    __syncthreads();   // sV + sP ready

    // ---- Phase B: O[c][qx] = sum_w V[c][w] P[w][qx].  Wave wv owns
    //      c-tiles 4wv..4wv+3, all 4 qx-tiles. ----
    f32x4 accO[4][4];
    #pragma unroll
    for (int mi = 0; mi < 4; ++mi)
        #pragma unroll
        for (int ni = 0; ni < 4; ++ni) accO[mi][ni] = (f32x4){0.f, 0.f, 0.f, 0.f};
    #pragma unroll
    for (int k0 = 0; k0 < 64; k0 += 32) {
        short8 av[4], bp[4];
        #pragma unroll
        for (int mi = 0; mi < 4; ++mi) av[mi] = *(const short8*)&sV[wv * 64 + mi * 16 + l15][k0 + q * 8];
        #pragma unroll
        for (int ni = 0; ni < 4; ++ni) bp[ni] = *(const short8*)&sP[ni * 16 + l15][k0 + q * 8];
        #pragma unroll
        for (int mi = 0; mi < 4; ++mi)
            #pragma unroll
            for (int ni = 0; ni < 4; ++ni)
                accO[mi][ni] = __builtin_amdgcn_mfma_f32_16x16x32_bf16(
                    av[mi], bp[ni], accO[mi][ni], 0, 0, 0);
    }

    #pragma unroll
    for (int ni = 0; ni < 4; ++ni) {
        const int qx = ni * 16 + l15;
        const int s = (MODE == 0) ? (fix * 64 + qx) : (qx * 64 + fix);
        u16* orow = vcatT + ((size_t)b * 4096 + s) * 512 + (MODE == 0 ? 0 : 256);
        #pragma unroll
        for (int mi = 0; mi < 4; ++mi) {
            const int c = wv * 64 + mi * 16 + q * 4;   // + r along contiguous c
            *(ushort4*)(orow + c) = make_ushort4(
                f2bs(accO[mi][ni][0]), f2bs(accO[mi][ni][1]),
                f2bs(accO[mi][ni][2]), f2bs(accO[mi][ni][3]));
        }
    }
}

// ---------------------------------------------------------------------------
// Proj GEMM: C[m=co][n=s] = sum_c wp[co][c]*vcatT[s][c], +BN+ReLU,
// fp32 out[b][co][s].  Both operands bf16 via global_load_lds.
// ---------------------------------------------------------------------------
__global__ __launch_bounds__(256) void k_proj(
    const u16* __restrict__ wp, const u16* __restrict__ Bt,
    const float* __restrict__ gamma, const float* __restrict__ beta,
    float* __restrict__ out)
{
    __shared__ u16 sA[128][32];
    __shared__ u16 sB[128][32];
    const int tid = threadIdx.x;
    const int lane = tid & 63, wave = tid >> 6;
    const int wm = (wave >> 1) * 64, wn = (wave & 1) * 64;
    const int l15 = lane & 15, q = lane >> 4;
    const int m0 = blockIdx.x * 128, n0 = blockIdx.y * 128;

    f32x4 acc[4][4];
    #pragma unroll
    for (int mi = 0; mi < 4; ++mi)
        #pragma unroll
        for (int ni = 0; ni < 4; ++ni) acc[mi][ni] = (f32x4){0.f, 0.f, 0.f, 0.f};

    for (int k0 = 0; k0 < 512; k0 += 32) {
        #pragma unroll
        for (int i = 0; i < 2; ++i) {            // wp: async 16B
            const int e = tid + i * 256;         // [0,512)
            const int ml = e >> 2, ch = e & 3;
            gl_lds16(wp + (size_t)(m0 + ml) * 512 + k0 + ch * 8,
                     &sA[0][0] + (size_t)e * 8);
        }
        #pragma unroll
        for (int i = 0; i < 2; ++i) {            // vcatT: async 16B
            const int e = tid + i * 256;
            const int nl = e >> 2, ch = e & 3;
            gl_lds16(Bt + (size_t)(n0 + nl) * 512 + k0 + ch * 8,
                     &sB[0][0] + (size_t)e * 8);
        }
        __syncthreads();
        short8 af[4], bf[4];
        #pragma unroll
        for (int mi = 0; mi < 4; ++mi) af[mi] = *(const short8*)&sA[wm + mi * 16 + l15][q * 8];
        #pragma unroll
        for (int ni = 0; ni < 4; ++ni) bf[ni] = *(const short8*)&sB[wn + ni * 16 + l15][q * 8];
        #pragma unroll
        for (int mi = 0; mi < 4; ++mi)
            #pragma unroll
            for (int ni = 0; ni < 4; ++ni)
                acc[mi][ni] = __builtin_amdgcn_mfma_f32_16x16x32_bf16(
                    af[mi], bf[ni], acc[mi][ni], 0, 0, 0);
        __syncthreads();
    }

    const float inv = rsqrtf(1.0f + BN_EPS);
    #pragma unroll
    for (int mi = 0; mi < 4; ++mi) {
        #pragma unroll
        for (int r = 0; r < 4; ++r) {
            const int m = m0 + wm + mi * 16 + q * 4 + r;
            const float sc = gamma[m] * inv, bb = beta[m];
            #pragma unroll
            for (int ni = 0; ni < 4; ++ni) {
                const int n = n0 + wn + ni * 16 + l15;
                const int b = n >> 12, s = n & 4095;
                const float v = acc[mi][ni][r] * sc + bb;
                out[((size_t)(b * 256 + m)) * 4096 + s] = fmaxf(v, 0.f);
            }
        }
    }
}

// ---------------------------------------------------------------------------
extern "C" void kernel_launch(void* const* d_in, const int* in_sizes, int n_in,
                              void* d_out, int out_size, void* d_ws, size_t ws_size,
                              hipStream_t stream) {
    const float* x      = (const float*)d_in[0];
    const float* w_qkv  = (const float*)d_in[1];
    const float* gamma1 = (const float*)d_in[2];
    const float* beta1  = (const float*)d_in[3];
    const float* w_proj = (const float*)d_in[4];
    const float* gamma2 = (const float*)d_in[5];
    const float* beta2  = (const float*)d_in[6];
    float* out = (float*)d_out;

    // ws: [0,64MiB) xt half-batch [32768][1024] bf16, reused as vcatT
    //     [65536][512]; [64,160MiB) qkvT [16][4096][768] bf16;
    //     [160,161.5MiB) wq bf16 [768][1024]; then wp bf16 [256][512].
    u16* xt    = (u16*)d_ws;
    u16* vcatT = (u16*)d_ws;
    u16* qkvT  = (u16*)((char*)d_ws + (size_t)64 * 1024 * 1024);
    u16* wq    = (u16*)((char*)d_ws + (size_t)160 * 1024 * 1024);
    u16* wp    = (u16*)((char*)d_ws + (size_t)160 * 1024 * 1024 + 2 * 1024 * 1024);

    k_wconv<<<896, 256, 0, stream>>>(w_qkv, w_proj, wq, wp);
    k_patchify<<<512, 256, 0, stream>>>(x, xt, 0);
    k_conv_gemm<<<dim3(256, 6), 256, 0, stream>>>(wq, xt, gamma1, beta1, qkvT, 0);
    k_patchify<<<512, 256, 0, stream>>>(x, xt, 8);
    k_conv_gemm<<<dim3(256, 6), 256, 0, stream>>>(wq, xt, gamma1, beta1, qkvT, 8);

    k_attn_mfma<0><<<dim3(16 * 64), 256, 0, stream>>>(qkvT, vcatT);
    k_attn_mfma<1><<<dim3(16 * 64), 256, 0, stream>>>(qkvT, vcatT);

    k_proj<<<dim3(2, 512), 256, 0, stream>>>(wp, vcatT, gamma2, beta2, out);
}